// Round 2
// baseline (4626.610 us; speedup 1.0000x reference)
//
#include <hip/hip_runtime.h>

// RecurrentEncoder persistent-kernel version.
// proj(16->512)+relu, 3-layer LSTM (H=512), out head (512->16). B=256, T=128.
// One persistent kernel: 192 WGs x 128 thr, 1 WG/CU (128 KB LDS), each WG owns
// (layer, 64 gate-cols, 128 batch rows) and loops t=0..127 with flag-based
// cross-WG sync. W in LDS for the whole run; c-state in registers; 32x32x16
// MFMA with swapped operands so gates land transpose-free in acc regs.

typedef __attribute__((ext_vector_type(8)))  short bf16x8;
typedef __attribute__((ext_vector_type(16))) float f32x16;
typedef __attribute__((ext_vector_type(4)))  float f32x4;
typedef __attribute__((ext_vector_type(8)))  unsigned short us8;

#define B_  256
#define T_  128
#define FIN 16
#define H_  512
#define G4  2048
#define MFMA32 __builtin_amdgcn_mfma_f32_32x32x16_bf16

static __device__ __forceinline__ float bf2f(unsigned short u){
  return __uint_as_float(((unsigned)u) << 16);
}
static __device__ __forceinline__ unsigned short f2bf(float f){  // RNE
  unsigned u = __float_as_uint(f);
  u += 0x7fffu + ((u >> 16) & 1u);
  return (unsigned short)(u >> 16);
}
static __device__ __forceinline__ float sigm(float x){ return 1.f/(1.f + __expf(-x)); }
static __device__ __forceinline__ float tanh_(float x){ return 1.f - 2.f/(__expf(2.f*x) + 1.f); }

static __device__ __forceinline__ void spin_ge(int* p, int v){
  while (__hip_atomic_load(p, __ATOMIC_RELAXED, __HIP_MEMORY_SCOPE_AGENT) < v)
    __builtin_amdgcn_s_sleep(2);
  __threadfence();  // acquire: invalidate stale L1/L2 before reading peer data
}

// ================= persistent-path kernels =================

// lstm_w fp32 [3][1024][2048] -> bf16, 32x32x16 A-frag order:
// wf[l][Jb=64][s=64][lane=64][e=8]; j' = Jb*32+(lane&31) (gate-interleaved
// j' = hcol*4+gate), k = s*16 + (lane>>5)*8 + e.
__global__ __launch_bounds__(256) void k_wconv(const float* __restrict__ w,
                                               unsigned short* __restrict__ wfo){
  long idx = (long)blockIdx.x*256 + threadIdx.x;   // 786432 = 3*64*64*64
  int lane = (int)(idx & 63);
  int s    = (int)((idx >> 6) & 63);
  int Jb   = (int)((idx >> 12) & 63);
  int l    = (int)(idx >> 18);
  int jp = Jb*32 + (lane & 31);
  int co = (jp & 3)*512 + (jp >> 2);       // orig col = gate*512 + hcol
  int k0 = s*16 + (lane >> 5)*8;
  us8 o;
  #pragma unroll
  for (int e = 0; e < 8; ++e)
    o[e] = f2bf(w[((long)(l*1024 + k0 + e))*2048 + co]);
  *(us8*)(wfo + idx*8) = o;
}

// xp = relu(x @ pw + pb) -> bf16, t-major: xpall[t][b][512]
__global__ __launch_bounds__(256) void k_xp(const float* __restrict__ x,
                                            const float* __restrict__ pw,
                                            const float* __restrict__ pb,
                                            unsigned short* __restrict__ xpall){
  __shared__ float sw[FIN*H_];
  __shared__ float sb[H_];
  int tid = threadIdx.x;
  for (int i = tid; i < FIN*H_; i += 256) sw[i] = pw[i];
  for (int i = tid; i < H_;     i += 256) sb[i] = pb[i];
  __syncthreads();
  int r0 = blockIdx.x * 64;
  int c0 = tid * 2;
  for (int rr = 0; rr < 64; ++rr){
    int r = r0 + rr;                       // flat b*T + t
    int b = r >> 7, t = r & 127;
    const float* xr = x + (long)r*FIN;
    float a0 = sb[c0], a1 = sb[c0+1];
    #pragma unroll
    for (int f = 0; f < FIN; ++f){
      float xv = xr[f];
      a0 += xv * sw[f*H_ + c0];
      a1 += xv * sw[f*H_ + c0 + 1];
    }
    ushort2 tmp;
    tmp.x = f2bf(fmaxf(a0, 0.f));
    tmp.y = f2bf(fmaxf(a1, 0.f));
    *(ushort2*)(xpall + ((long)t*256 + b)*512 + c0) = tmp;
  }
}

// y = h2all @ out_w + out_b ; h2all is t-major [t][b][512]
__global__ __launch_bounds__(256) void k_out(const unsigned short* __restrict__ h2,
                                             const float* __restrict__ ow,
                                             const float* __restrict__ ob,
                                             float* __restrict__ dout){
  __shared__ float sw[H_*16];
  int tid = threadIdx.x;
  for (int i = tid; i < H_*16; i += 256) sw[i] = ow[i];
  __syncthreads();
  int r0 = blockIdx.x * 128;
  #pragma unroll
  for (int q = 0; q < 8; ++q){
    int oid = tid + 256*q;
    int rr = oid >> 4, o = oid & 15;
    int r = r0 + rr;                        // flat b*T + t
    int b = r >> 7, t = r & 127;
    const us8* hp = (const us8*)(h2 + ((long)t*256 + b)*512);
    float acc = ob[o];
    for (int k8 = 0; k8 < H_/8; ++k8){
      us8 v = hp[k8];
      #pragma unroll
      for (int e = 0; e < 8; ++e) acc += bf2f(v[e]) * sw[(k8*8 + e)*16 + o];
    }
    dout[(long)r*16 + o] = acc;
  }
}

#define CELL(ACC, JB, RF) \
  { _Pragma("unroll") \
    for (int q = 0; q < 4; ++q){ \
      float iv = ACC[4*q+0], gv = ACC[4*q+1], fv = ACC[4*q+2], ov = ACC[4*q+3]; \
      float cp = cst[JB][RF][q]; \
      float cn = sigm(fv + 1.f)*cp + sigm(iv)*tanh_(gv); \
      float hn = sigm(ov)*tanh_(cn); \
      cst[JB][RF][q] = cn; \
      int row = row0 + RF*32 + l31; \
      int hc  = (n*2 + JB)*8 + 2*q + l5; \
      hw[(long)row*512 + hc] = f2bf(hn); \
      if (l < 2) hrw[(long)row*512 + hc] = f2bf(fmaxf(hn, 0.f)); \
      else h2all[((long)t*256 + row)*512 + hc] = f2bf(hn); \
    } }

// Persistent RNN kernel. grid 192 = (l:3) x (n:32) x (mg:2); block 128 (2 waves).
// LDS: W slice [2 Jb][64 s][64 lane][16B] = 128 KB, resident all 128 timesteps.
__global__ __launch_bounds__(128, 1) void k_rnn(
    const unsigned short* __restrict__ wf, const float* __restrict__ lb,
    unsigned short* __restrict__ hb, unsigned short* __restrict__ hrl,
    const unsigned short* __restrict__ xpall, unsigned short* __restrict__ h2all,
    int* __restrict__ flags)
{
  extern __shared__ unsigned char Wl[];    // 131072 B
  const int tid = threadIdx.x;
  const int wg  = blockIdx.x;
  const int mg  = wg & 1;
  const int n   = (wg >> 1) & 31;
  const int l   = wg >> 6;
  const int lane = tid & 63;
  const int wv   = tid >> 6;               // wave 0/1 -> rows wv*64
  const int l5 = lane >> 5, l31 = lane & 31;

  // ---- preload W slice into LDS (once) ----
  {
    const us8* src = (const us8*)(wf + ((long)(l*64 + n*2))*64*64*8);
    us8* dst = (us8*)Wl;
    for (int i = tid; i < 8192; i += 128) dst[i] = src[i];
  }
  // ---- bias into regs (acc-init vectors, layout matches D frag) ----
  f32x16 bias0, bias1;
  #pragma unroll
  for (int r = 0; r < 16; ++r){
    int hc0 = (n*2 + 0)*8 + 2*(r>>2) + l5;
    int hc1 = (n*2 + 1)*8 + 2*(r>>2) + l5;
    bias0[r] = lb[l*G4 + (r&3)*512 + hc0];
    bias1[r] = lb[l*G4 + (r&3)*512 + hc1];
  }
  float cst[2][2][4] = {};                 // c-state, register-resident
  __syncthreads();

  const int row0 = mg*128 + wv*64;         // + rf*32 + l31
  int* fOwn  = flags + (l*2 + mg);
  int* fPrev = flags + ((l-1)*2 + mg);
  int* fNext = flags + ((l+1)*2 + mg);

  for (int t = 0; t < T_; ++t){
    const int pw = t & 1, pr = pw ^ 1;
    // W1: own group stage t-1 done (h[l][t-1] ready; also WAR on hb).
    // W3: layer-above group done with stage t-2 (WAR on hrl we overwrite).
    if (tid == 0){
      if (t > 0)           spin_ge(fOwn, 32*t);
      if (l < 2 && t >= 2) spin_ge(fNext, 32*(t-1));
    }
    __syncthreads();

    f32x16 a00 = bias0, a01 = bias0, a10 = bias1, a11 = bias1;  // a{jb}{rf}

    // ---- right half: k in [512,1024) = own h_prev ----
    {
      const unsigned short* r0p = hb + ((long)(pr*3 + l)*256 + row0 + l31)*512 + l5*8;
      const unsigned short* r1p = r0p + 32*512;
      #pragma unroll
      for (int s = 32; s < 64; ++s){
        bf16x8 w0 = *(const bf16x8*)(Wl + (((0*64 + s)*64 + lane) << 4));
        bf16x8 w1 = *(const bf16x8*)(Wl + (((1*64 + s)*64 + lane) << 4));
        bf16x8 b0 = *(const bf16x8*)(r0p + (s-32)*16);
        bf16x8 b1 = *(const bf16x8*)(r1p + (s-32)*16);
        a00 = MFMA32(w0, b0, a00, 0, 0, 0);
        a01 = MFMA32(w0, b1, a01, 0, 0, 0);
        a10 = MFMA32(w1, b0, a10, 0, 0, 0);
        a11 = MFMA32(w1, b1, a11, 0, 0, 0);
      }
    }
    // W2: layer below finished stage t (left input ready)
    if (l > 0){
      if (tid == 0) spin_ge(fPrev, 32*(t+1));
      __syncthreads();
    }
    // ---- left half: k in [0,512) = xp (l==0) or relu(h[l-1][t]) ----
    {
      const unsigned short* lsrc = (l == 0)
          ? xpall + (long)t*256*512
          : hrl + (long)(pw*3 + (l-1))*256*512;
      const unsigned short* l0p = lsrc + ((long)(row0 + l31))*512 + l5*8;
      const unsigned short* l1p = l0p + 32*512;
      #pragma unroll
      for (int s = 0; s < 32; ++s){
        bf16x8 w0 = *(const bf16x8*)(Wl + (((0*64 + s)*64 + lane) << 4));
        bf16x8 w1 = *(const bf16x8*)(Wl + (((1*64 + s)*64 + lane) << 4));
        bf16x8 b0 = *(const bf16x8*)(l0p + s*16);
        bf16x8 b1 = *(const bf16x8*)(l1p + s*16);
        a00 = MFMA32(w0, b0, a00, 0, 0, 0);
        a01 = MFMA32(w0, b1, a01, 0, 0, 0);
        a10 = MFMA32(w1, b0, a10, 0, 0, 0);
        a11 = MFMA32(w1, b1, a11, 0, 0, 0);
      }
    }
    // ---- LSTM cell (all in regs; D frag: lane = batch row, regs = j') ----
    {
      unsigned short* hw  = hb  + (long)(pw*3 + l)*256*512;
      unsigned short* hrw = hrl + (long)(pw*3 + l)*256*512;
      CELL(a00, 0, 0)
      CELL(a01, 0, 1)
      CELL(a10, 1, 0)
      CELL(a11, 1, 1)
    }
    __syncthreads();                       // drain all 128 threads' h writes
    if (tid == 0){
      __threadfence();                     // release: flush to device scope
      __hip_atomic_fetch_add(fOwn, 1, __ATOMIC_RELAXED, __HIP_MEMORY_SCOPE_AGENT);
    }
  }
}

// ================= round-0 fallback (compact) kernels =================

__global__ __launch_bounds__(256) void k_wconv0(const float* __restrict__ w,
                                                unsigned short* __restrict__ wf){
  long d8 = ((long)blockIdx.x*256 + threadIdx.x) * 8;
  int lane = (int)((d8 >> 3) & 63);
  int s    = (int)((d8 >> 9) & 31);
  int J    = (int)((d8 >> 14) & 127);
  int l    = (int)(d8 >> 21);
  int jj = lane & 15, khi = lane >> 4;
  int jp = J*16 + jj;
  int co = (jp & 3)*512 + (jp >> 2);
  int kbase = s*32 + khi*8;
  us8 o;
  #pragma unroll
  for (int e = 0; e < 8; ++e)
    o[e] = f2bf(w[((long)(l*1024 + kbase + e))*2048 + co]);
  *(us8*)(wf + d8) = o;
}

__global__ void k_iout(float* __restrict__ dout, const float* __restrict__ ob){
  int i = blockIdx.x*256 + threadIdx.x;
  if (i < B_*T_*16) dout[i] = ob[i & 15];
}

__global__ __launch_bounds__(256, 2) void k_stage0(
    const float* __restrict__ x, const float* __restrict__ pw, const float* __restrict__ pb,
    const unsigned short* __restrict__ wf, const float* __restrict__ lb,
    const float* __restrict__ ow, float* __restrict__ dout,
    float* __restrict__ cbuf, unsigned short* __restrict__ hb,
    int t, int l)
{
  __shared__ unsigned char Ab[32*2048];
  __shared__ float gsm[32*36];
  __shared__ float xrow[32*16];
  __shared__ float hcell[32*8];

  const int tid = threadIdx.x;
  const int bid = blockIdx.x;
  const int m = bid >> 6;
  const int n = ((bid & 7) << 3) | ((bid >> 3) & 7);
  const int pwr = t & 1, prd = pwr ^ 1;
  const int bg0 = m * 32;

  {
    const unsigned short* src = hb + (((long)prd*3 + l)*256 + bg0)*512;
    for (int i = 0; i < 8; ++i){
      int cid = tid + 256*i;
      int row = cid >> 6, cc = cid & 63;
      us8 v = *(const us8*)(src + (long)row*512 + cc*8);
      *(us8*)(Ab + ((row*2048 + 1024 + cc*16) ^ ((row & 7) << 4))) = v;
    }
  }
  if (l > 0){
    const unsigned short* src = hb + (((long)pwr*3 + (l-1))*256 + bg0)*512;
    for (int i = 0; i < 8; ++i){
      int cid = tid + 256*i;
      int row = cid >> 6, cc = cid & 63;
      us8 v = *(const us8*)(src + (long)row*512 + cc*8);
      #pragma unroll
      for (int e = 0; e < 8; ++e) v[e] = (v[e] & 0x8000u) ? (unsigned short)0 : v[e];
      *(us8*)(Ab + ((row*2048 + cc*16) ^ ((row & 7) << 4))) = v;
    }
  } else {
    {
      int e2 = tid*2;
      int br = e2 >> 4, f = e2 & 15;
      const float* xr = x + ((long)(bg0 + br)*T_ + t)*FIN;
      xrow[e2] = xr[f]; xrow[e2+1] = xr[f+1];
    }
    __syncthreads();
    for (int i = 0; i < 8; ++i){
      int cid = tid + 256*i;
      int row = cid >> 6, cc = cid & 63;
      int c0 = cc*8;
      us8 vv;
      #pragma unroll
      for (int j = 0; j < 8; ++j){
        float a = pb[c0 + j];
        #pragma unroll
        for (int f = 0; f < FIN; ++f) a += xrow[row*16 + f] * pw[f*H_ + c0 + j];
        vv[j] = f2bf(fmaxf(a, 0.f));
      }
      *(us8*)(Ab + ((row*2048 + cc*16) ^ ((row & 7) << 4))) = vv;
    }
  }
  __syncthreads();

  const int lane = tid & 63, wid = tid >> 6;
  const int wm = wid >> 1, wn = wid & 1;
  const int J = n*2 + wn;
  const int arow = wm*16 + (lane & 15);
  const unsigned abase = (unsigned)arow*2048 + ((lane >> 4) << 4);
  const unsigned axor = (unsigned)((arow & 7) << 4);
  const unsigned short* bp = wf + ((((long)l*128 + J)*32)*64 + lane)*8;

  f32x4 acc = {0.f, 0.f, 0.f, 0.f};
  #pragma unroll
  for (int s = 0; s < 32; ++s){
    bf16x8 af = *(const bf16x8*)(Ab + ((abase + s*64) ^ axor));
    bf16x8 bfr = *(const bf16x8*)(bp + (long)s*512);
    acc = __builtin_amdgcn_mfma_f32_16x16x32_bf16(af, bfr, acc, 0, 0, 0);
  }
  {
    int colb = wn*16 + (lane & 15);
    int rowb = wm*16 + ((lane >> 4) << 2);
    #pragma unroll
    for (int r = 0; r < 4; ++r) gsm[(rowb + r)*36 + colb] = acc[r];
  }
  __syncthreads();

  {
    int bl = tid >> 3, hc = tid & 7;
    float4 g4 = *(float4*)(&gsm[bl*36 + hc*4]);
    int hcol = n*8 + hc;
    int bgl = bg0 + bl;
    float iv = g4.x + lb[l*G4 + hcol];
    float gv = g4.y + lb[l*G4 + 512 + hcol];
    float fv = g4.z + lb[l*G4 + 1024 + hcol];
    float ov = g4.w + lb[l*G4 + 1536 + hcol];
    long coff = ((long)l*256 + bgl)*512 + hcol;
    float cp = cbuf[coff];
    float cn = sigm(fv + 1.f)*cp + sigm(iv)*tanh_(gv);
    float hn = sigm(ov)*tanh_(cn);
    cbuf[coff] = cn;
    hb[(((long)pwr*3 + l)*256 + bgl)*512 + hcol] = f2bf(hn);
    if (l == 2) hcell[bl*8 + hc] = hn;
  }
  if (l == 2){
    __syncthreads();
    #pragma unroll
    for (int q = 0; q < 2; ++q){
      int oid = tid + 256*q;
      int bl = oid >> 4, o = oid & 15;
      float a = 0.f;
      #pragma unroll
      for (int hc = 0; hc < 8; ++hc) a += hcell[bl*8 + hc] * ow[(n*8 + hc)*16 + o];
      atomicAdd(dout + ((long)(bg0 + bl)*T_ + t)*16 + o, a);
    }
  }
}

// ================= launch =================

extern "C" void kernel_launch(void* const* d_in, const int* in_sizes, int n_in,
                              void* d_out, int out_size, void* d_ws, size_t ws_size,
                              hipStream_t stream)
{
  const float* x  = (const float*)d_in[0];
  const float* pw = (const float*)d_in[1];
  const float* pb = (const float*)d_in[2];
  const float* lw = (const float*)d_in[3];
  const float* lb = (const float*)d_in[4];
  const float* ow = (const float*)d_in[5];
  const float* ob = (const float*)d_in[6];
  float* dout = (float*)d_out;

  char* ws = (char*)d_ws;
  size_t off = 0;
  auto carve = [&](size_t bytes){ char* p = ws + off; off += (bytes + 255) & ~(size_t)255; return p; };
  unsigned short* wf    = (unsigned short*)carve(3ull*64*64*64*8*2);   // 12.58 MB
  unsigned short* hbuf  = (unsigned short*)carve(2ull*3*256*512*2);    // 1.57 MB
  unsigned short* hrl   = (unsigned short*)carve(2ull*3*256*512*2);    // 1.57 MB
  int*            flags = (int*)carve(64);
  unsigned short* xpall = (unsigned short*)carve((size_t)B_*T_*H_*2);  // 33.55 MB
  unsigned short* h2all = (unsigned short*)carve((size_t)B_*T_*H_*2);  // 33.55 MB
  size_t need_lux = off;

  bool lux = (ws_size >= need_lux);
  if (lux)
    lux = (hipFuncSetAttribute((const void*)k_rnn,
                               hipFuncAttributeMaxDynamicSharedMemorySize,
                               131072) == hipSuccess);

  if (lux){
    // zero h, hrelu, flags (contiguous carves)
    hipMemsetAsync(hbuf, 0, 2ull*3*256*512*2*2 + 256 + 256, stream);
    k_wconv<<<3072, 256, 0, stream>>>(lw, wf);
    k_xp<<<512, 256, 0, stream>>>(x, pw, pb, xpall);
    k_rnn<<<192, 128, 131072, stream>>>(wf, lb, hbuf, hrl, xpall, h2all, flags);
    k_out<<<256, 256, 0, stream>>>(h2all, ow, ob, dout);
  } else {
    // round-0 compact fallback: reuse carve region with old layout
    size_t o2 = 0;
    auto carve2 = [&](size_t bytes){ char* p = ws + o2; o2 += (bytes + 255) & ~(size_t)255; return p; };
    unsigned short* wf0   = (unsigned short*)carve2(3ull*1024*2048*2);
    float*          cbuf  = (float*)carve2(3ull*256*512*4);
    unsigned short* hbuf0 = (unsigned short*)carve2(2ull*3*256*512*2);
    hipMemsetAsync(cbuf, 0, 3ull*256*512*4 + 2ull*3*256*512*2, stream);
    k_wconv0<<<3072, 256, 0, stream>>>(lw, wf0);
    k_iout<<<2048, 256, 0, stream>>>(dout, ob);
    for (int t = 0; t < T_; ++t)
      for (int l = 0; l < 3; ++l)
        k_stage0<<<512, 256, 0, stream>>>(x, pw, pb, wf0, lb, ow, dout,
                                          cbuf, hbuf0, t, l);
  }
}

// Round 3
// 3090.975 us; speedup vs baseline: 1.4968x; 1.4968x over previous
//
#include <hip/hip_runtime.h>

// RecurrentEncoder: proj(16->512)+relu, 3-layer LSTM (H=512), out head (512->16).
// B=256, T=128. Round 3: anti-diagonal launch batching (130 launches of up to 3
// independent (t,l) stages), LDS-free stage kernel using the round-1-verified
// 32x32x16 swapped-operand MFMA (A=W from global in frag order, B=activations,
// gates land transpose-free in acc regs, fp32 cell inline).

typedef __attribute__((ext_vector_type(8)))  short bf16x8;
typedef __attribute__((ext_vector_type(16))) float f32x16;
typedef __attribute__((ext_vector_type(4)))  float f32x4;
typedef __attribute__((ext_vector_type(8)))  unsigned short us8;

#define B_  256
#define T_  128
#define FIN 16
#define H_  512
#define G4  2048
#define MFMA32 __builtin_amdgcn_mfma_f32_32x32x16_bf16

static __device__ __forceinline__ float bf2f(unsigned short u){
  return __uint_as_float(((unsigned)u) << 16);
}
static __device__ __forceinline__ unsigned short f2bf(float f){  // RNE
  unsigned u = __float_as_uint(f);
  u += 0x7fffu + ((u >> 16) & 1u);
  return (unsigned short)(u >> 16);
}
static __device__ __forceinline__ float sigm(float x){ return 1.f/(1.f + __expf(-x)); }
static __device__ __forceinline__ float tanh_(float x){ return 1.f - 2.f/(__expf(2.f*x) + 1.f); }

// ================= prep kernels (verified round 1) =================

// lstm_w fp32 [3][1024][2048] -> bf16, 32x32x16 A-frag order:
// wf[l][Jb=64][s=64][lane=64][e=8]; j' = Jb*32+(lane&31) (gate-interleaved
// j' = hcol*4+gate), k = s*16 + (lane>>5)*8 + e.
__global__ __launch_bounds__(256) void k_wconv(const float* __restrict__ w,
                                               unsigned short* __restrict__ wfo){
  long idx = (long)blockIdx.x*256 + threadIdx.x;   // 786432 = 3*64*64*64
  int lane = (int)(idx & 63);
  int s    = (int)((idx >> 6) & 63);
  int Jb   = (int)((idx >> 12) & 63);
  int l    = (int)(idx >> 18);
  int jp = Jb*32 + (lane & 31);
  int co = (jp & 3)*512 + (jp >> 2);       // orig col = gate*512 + hcol
  int k0 = s*16 + (lane >> 5)*8;
  us8 o;
  #pragma unroll
  for (int e = 0; e < 8; ++e)
    o[e] = f2bf(w[((long)(l*1024 + k0 + e))*2048 + co]);
  *(us8*)(wfo + idx*8) = o;
}

// xp = relu(x @ pw + pb) -> bf16, t-major: xpall[t][b][512]
__global__ __launch_bounds__(256) void k_xp(const float* __restrict__ x,
                                            const float* __restrict__ pw,
                                            const float* __restrict__ pb,
                                            unsigned short* __restrict__ xpall){
  __shared__ float sw[FIN*H_];
  __shared__ float sb[H_];
  int tid = threadIdx.x;
  for (int i = tid; i < FIN*H_; i += 256) sw[i] = pw[i];
  for (int i = tid; i < H_;     i += 256) sb[i] = pb[i];
  __syncthreads();
  int r0 = blockIdx.x * 64;
  int c0 = tid * 2;
  for (int rr = 0; rr < 64; ++rr){
    int r = r0 + rr;                       // flat b*T + t
    int b = r >> 7, t = r & 127;
    const float* xr = x + (long)r*FIN;
    float a0 = sb[c0], a1 = sb[c0+1];
    #pragma unroll
    for (int f = 0; f < FIN; ++f){
      float xv = xr[f];
      a0 += xv * sw[f*H_ + c0];
      a1 += xv * sw[f*H_ + c0 + 1];
    }
    ushort2 tmp;
    tmp.x = f2bf(fmaxf(a0, 0.f));
    tmp.y = f2bf(fmaxf(a1, 0.f));
    *(ushort2*)(xpall + ((long)t*256 + b)*512 + c0) = tmp;
  }
}

// y = h2all @ out_w + out_b ; h2all is t-major [t][b][512]
__global__ __launch_bounds__(256) void k_out(const unsigned short* __restrict__ h2,
                                             const float* __restrict__ ow,
                                             const float* __restrict__ ob,
                                             float* __restrict__ dout){
  __shared__ float sw[H_*16];
  int tid = threadIdx.x;
  for (int i = tid; i < H_*16; i += 256) sw[i] = ow[i];
  __syncthreads();
  int r0 = blockIdx.x * 128;
  #pragma unroll
  for (int q = 0; q < 8; ++q){
    int oid = tid + 256*q;
    int rr = oid >> 4, o = oid & 15;
    int r = r0 + rr;                        // flat b*T + t
    int b = r >> 7, t = r & 127;
    const us8* hp = (const us8*)(h2 + ((long)t*256 + b)*512);
    float acc = ob[o];
    for (int k8 = 0; k8 < H_/8; ++k8){
      us8 v = hp[k8];
      #pragma unroll
      for (int e = 0; e < 8; ++e) acc += bf2f(v[e]) * sw[(k8*8 + e)*16 + o];
    }
    dout[(long)r*16 + o] = acc;
  }
}

// ================= diagonal stage kernel =================

#define CELLG(ACC, JB, RF) \
  { _Pragma("unroll") \
    for (int q = 0; q < 4; ++q){ \
      float iv = ACC[4*q+0], gv = ACC[4*q+1], fv = ACC[4*q+2], ov = ACC[4*q+3]; \
      int row = row0 + RF*32 + l31; \
      int hc  = (n*2 + JB)*8 + 2*q + l5; \
      long coff = ((long)l*256 + row)*512 + hc; \
      float cp = cbuf[coff]; \
      float cn = sigm(fv + 1.f)*cp + sigm(iv)*tanh_(gv); \
      float hn = sigm(ov)*tanh_(cn); \
      cbuf[coff] = cn; \
      hw[(long)row*512 + hc] = f2bf(hn); \
      if (l < 2) hrw[(long)row*512 + hc] = f2bf(fmaxf(hn, 0.f)); \
      else h2all[((long)t*256 + row)*512 + hc] = f2bf(hn); \
    } }

// One launch = all stages (t,l) with t+l == d (independent). grid = 64*nst,
// block 128 (2 waves). WG handles 64 gate-cols (2 Jb of 32 j') x 128 rows.
// n's low 3 bits = bid&7 so each XCD re-reads the same W slice every launch.
__global__ __launch_bounds__(128, 1) void k_diag(
    const unsigned short* __restrict__ wf, const float* __restrict__ lb,
    float* __restrict__ cbuf, unsigned short* __restrict__ hb,
    unsigned short* __restrict__ hrl, const unsigned short* __restrict__ xpall,
    unsigned short* __restrict__ h2all, int d, int l0)
{
  const int tid  = threadIdx.x;
  const int bid  = blockIdx.x;
  const int sidx = bid >> 6;
  const int wg   = bid & 63;
  const int l    = l0 + sidx;
  const int t    = d - l;
  const int n    = ((wg & 7) << 2) | ((wg >> 3) & 3);  // XCD-pinned gate group
  const int mg   = (wg >> 5) & 1;
  const int lane = tid & 63;
  const int wv   = tid >> 6;
  const int l5 = lane >> 5, l31 = lane & 31;
  const int row0 = mg*128 + wv*64;
  const int pw = t & 1, pr = pw ^ 1;

  // acc init = bias (D frag: row j'_local = (r&3) + 8*(r>>2) + 4*l5)
  f32x16 a00, a01, a10, a11;
  #pragma unroll
  for (int r = 0; r < 16; ++r){
    int hc0 = (n*2 + 0)*8 + 2*(r>>2) + l5;
    int hc1 = (n*2 + 1)*8 + 2*(r>>2) + l5;
    float b0v = lb[l*G4 + (r&3)*512 + hc0];
    float b1v = lb[l*G4 + (r&3)*512 + hc1];
    a00[r] = b0v; a01[r] = b0v; a10[r] = b1v; a11[r] = b1v;
  }

  const unsigned short* w0base = wf + ((long)(l*64 + n*2 + 0))*4096*8;
  const unsigned short* w1base = wf + ((long)(l*64 + n*2 + 1))*4096*8;

  // ---- right half: k in [512,1024) = own h_prev ----
  {
    const unsigned short* r0p = hb + (((long)(pr*3 + l))*256 + row0 + l31)*512 + l5*8;
    const unsigned short* r1p = r0p + 32*512;
    #pragma unroll 8
    for (int s = 32; s < 64; ++s){
      bf16x8 w0 = *(const bf16x8*)(w0base + ((long)s*64 + lane)*8);
      bf16x8 w1 = *(const bf16x8*)(w1base + ((long)s*64 + lane)*8);
      bf16x8 b0 = *(const bf16x8*)(r0p + (s-32)*16);
      bf16x8 b1 = *(const bf16x8*)(r1p + (s-32)*16);
      a00 = MFMA32(w0, b0, a00, 0, 0, 0);
      a01 = MFMA32(w0, b1, a01, 0, 0, 0);
      a10 = MFMA32(w1, b0, a10, 0, 0, 0);
      a11 = MFMA32(w1, b1, a11, 0, 0, 0);
    }
  }
  // ---- left half: k in [0,512) = xp (l==0) or relu(h[l-1][t]) ----
  {
    const unsigned short* lsrc = (l == 0)
        ? xpall + (long)t*256*512
        : hrl + (long)(pw*2 + (l-1))*256*512;
    const unsigned short* l0p = lsrc + ((long)(row0 + l31))*512 + l5*8;
    const unsigned short* l1p = l0p + 32*512;
    #pragma unroll 8
    for (int s = 0; s < 32; ++s){
      bf16x8 w0 = *(const bf16x8*)(w0base + ((long)s*64 + lane)*8);
      bf16x8 w1 = *(const bf16x8*)(w1base + ((long)s*64 + lane)*8);
      bf16x8 b0 = *(const bf16x8*)(l0p + s*16);
      bf16x8 b1 = *(const bf16x8*)(l1p + s*16);
      a00 = MFMA32(w0, b0, a00, 0, 0, 0);
      a01 = MFMA32(w0, b1, a01, 0, 0, 0);
      a10 = MFMA32(w1, b0, a10, 0, 0, 0);
      a11 = MFMA32(w1, b1, a11, 0, 0, 0);
    }
  }
  // ---- LSTM cell, all in regs (verified layout) ----
  {
    unsigned short* hw  = hb + (long)(pw*3 + l)*256*512;
    unsigned short* hrw = (l < 2) ? (hrl + (long)(pw*2 + l)*256*512) : (unsigned short*)0;
    CELLG(a00, 0, 0)
    CELLG(a01, 0, 1)
    CELLG(a10, 1, 0)
    CELLG(a11, 1, 1)
  }
}

// ================= round-0 fallback (compact) kernels =================

__global__ __launch_bounds__(256) void k_wconv0(const float* __restrict__ w,
                                                unsigned short* __restrict__ wf){
  long d8 = ((long)blockIdx.x*256 + threadIdx.x) * 8;
  int lane = (int)((d8 >> 3) & 63);
  int s    = (int)((d8 >> 9) & 31);
  int J    = (int)((d8 >> 14) & 127);
  int l    = (int)(d8 >> 21);
  int jj = lane & 15, khi = lane >> 4;
  int jp = J*16 + jj;
  int co = (jp & 3)*512 + (jp >> 2);
  int kbase = s*32 + khi*8;
  us8 o;
  #pragma unroll
  for (int e = 0; e < 8; ++e)
    o[e] = f2bf(w[((long)(l*1024 + kbase + e))*2048 + co]);
  *(us8*)(wf + d8) = o;
}

__global__ void k_iout(float* __restrict__ dout, const float* __restrict__ ob){
  int i = blockIdx.x*256 + threadIdx.x;
  if (i < B_*T_*16) dout[i] = ob[i & 15];
}

__global__ __launch_bounds__(256, 2) void k_stage0(
    const float* __restrict__ x, const float* __restrict__ pw, const float* __restrict__ pb,
    const unsigned short* __restrict__ wf, const float* __restrict__ lb,
    const float* __restrict__ ow, float* __restrict__ dout,
    float* __restrict__ cbuf, unsigned short* __restrict__ hb,
    int t, int l)
{
  __shared__ unsigned char Ab[32*2048];
  __shared__ float gsm[32*36];
  __shared__ float xrow[32*16];
  __shared__ float hcell[32*8];

  const int tid = threadIdx.x;
  const int bid = blockIdx.x;
  const int m = bid >> 6;
  const int n = ((bid & 7) << 3) | ((bid >> 3) & 7);
  const int pwr = t & 1, prd = pwr ^ 1;
  const int bg0 = m * 32;

  {
    const unsigned short* src = hb + (((long)prd*3 + l)*256 + bg0)*512;
    for (int i = 0; i < 8; ++i){
      int cid = tid + 256*i;
      int row = cid >> 6, cc = cid & 63;
      us8 v = *(const us8*)(src + (long)row*512 + cc*8);
      *(us8*)(Ab + ((row*2048 + 1024 + cc*16) ^ ((row & 7) << 4))) = v;
    }
  }
  if (l > 0){
    const unsigned short* src = hb + (((long)pwr*3 + (l-1))*256 + bg0)*512;
    for (int i = 0; i < 8; ++i){
      int cid = tid + 256*i;
      int row = cid >> 6, cc = cid & 63;
      us8 v = *(const us8*)(src + (long)row*512 + cc*8);
      #pragma unroll
      for (int e = 0; e < 8; ++e) v[e] = (v[e] & 0x8000u) ? (unsigned short)0 : v[e];
      *(us8*)(Ab + ((row*2048 + cc*16) ^ ((row & 7) << 4))) = v;
    }
  } else {
    {
      int e2 = tid*2;
      int br = e2 >> 4, f = e2 & 15;
      const float* xr = x + ((long)(bg0 + br)*T_ + t)*FIN;
      xrow[e2] = xr[f]; xrow[e2+1] = xr[f+1];
    }
    __syncthreads();
    for (int i = 0; i < 8; ++i){
      int cid = tid + 256*i;
      int row = cid >> 6, cc = cid & 63;
      int c0 = cc*8;
      us8 vv;
      #pragma unroll
      for (int j = 0; j < 8; ++j){
        float a = pb[c0 + j];
        #pragma unroll
        for (int f = 0; f < FIN; ++f) a += xrow[row*16 + f] * pw[f*H_ + c0 + j];
        vv[j] = f2bf(fmaxf(a, 0.f));
      }
      *(us8*)(Ab + ((row*2048 + cc*16) ^ ((row & 7) << 4))) = vv;
    }
  }
  __syncthreads();

  const int lane = tid & 63, wid = tid >> 6;
  const int wm = wid >> 1, wn = wid & 1;
  const int J = n*2 + wn;
  const int arow = wm*16 + (lane & 15);
  const unsigned abase = (unsigned)arow*2048 + ((lane >> 4) << 4);
  const unsigned axor = (unsigned)((arow & 7) << 4);
  const unsigned short* bp = wf + ((((long)l*128 + J)*32)*64 + lane)*8;

  f32x4 acc = {0.f, 0.f, 0.f, 0.f};
  #pragma unroll
  for (int s = 0; s < 32; ++s){
    bf16x8 af = *(const bf16x8*)(Ab + ((abase + s*64) ^ axor));
    bf16x8 bfr = *(const bf16x8*)(bp + (long)s*512);
    acc = __builtin_amdgcn_mfma_f32_16x16x32_bf16(af, bfr, acc, 0, 0, 0);
  }
  {
    int colb = wn*16 + (lane & 15);
    int rowb = wm*16 + ((lane >> 4) << 2);
    #pragma unroll
    for (int r = 0; r < 4; ++r) gsm[(rowb + r)*36 + colb] = acc[r];
  }
  __syncthreads();

  {
    int bl = tid >> 3, hc = tid & 7;
    float4 g4 = *(float4*)(&gsm[bl*36 + hc*4]);
    int hcol = n*8 + hc;
    int bgl = bg0 + bl;
    float iv = g4.x + lb[l*G4 + hcol];
    float gv = g4.y + lb[l*G4 + 512 + hcol];
    float fv = g4.z + lb[l*G4 + 1024 + hcol];
    float ov = g4.w + lb[l*G4 + 1536 + hcol];
    long coff = ((long)l*256 + bgl)*512 + hcol;
    float cp = cbuf[coff];
    float cn = sigm(fv + 1.f)*cp + sigm(iv)*tanh_(gv);
    float hn = sigm(ov)*tanh_(cn);
    cbuf[coff] = cn;
    hb[(((long)pwr*3 + l)*256 + bgl)*512 + hcol] = f2bf(hn);
    if (l == 2) hcell[bl*8 + hc] = hn;
  }
  if (l == 2){
    __syncthreads();
    #pragma unroll
    for (int q = 0; q < 2; ++q){
      int oid = tid + 256*q;
      int bl = oid >> 4, o = oid & 15;
      float a = 0.f;
      #pragma unroll
      for (int hc = 0; hc < 8; ++hc) a += hcell[bl*8 + hc] * ow[(n*8 + hc)*16 + o];
      atomicAdd(dout + ((long)(bg0 + bl)*T_ + t)*16 + o, a);
    }
  }
}

// ================= launch =================

extern "C" void kernel_launch(void* const* d_in, const int* in_sizes, int n_in,
                              void* d_out, int out_size, void* d_ws, size_t ws_size,
                              hipStream_t stream)
{
  const float* x  = (const float*)d_in[0];
  const float* pw = (const float*)d_in[1];
  const float* pb = (const float*)d_in[2];
  const float* lw = (const float*)d_in[3];
  const float* lb = (const float*)d_in[4];
  const float* ow = (const float*)d_in[5];
  const float* ob = (const float*)d_in[6];
  float* dout = (float*)d_out;

  char* ws = (char*)d_ws;
  size_t off = 0;
  auto carve = [&](size_t bytes){ char* p = ws + off; off += (bytes + 255) & ~(size_t)255; return p; };
  unsigned short* wf    = (unsigned short*)carve(3ull*64*4096*8*2);    // 12.58 MB
  float*          cbuf  = (float*)carve(3ull*256*512*4);               // 1.57 MB
  unsigned short* hbuf  = (unsigned short*)carve(2ull*3*256*512*2);    // 1.57 MB
  unsigned short* hrl   = (unsigned short*)carve(2ull*2*256*512*2);    // 1.05 MB
  unsigned short* xpall = (unsigned short*)carve((size_t)B_*T_*H_*2);  // 33.55 MB
  unsigned short* h2all = (unsigned short*)carve((size_t)B_*T_*H_*2);  // 33.55 MB
  size_t need_lux = off;                                               // 80.0 MiB

  bool lux = (ws_size >= need_lux);

  if (lux){
    // zero c + h (both parities) + hrelu: contiguous carves, 4 MiB total
    hipMemsetAsync(cbuf, 0, 3ull*256*512*4 + 2ull*3*256*512*2 + 2ull*2*256*512*2, stream);
    k_wconv<<<3072, 256, 0, stream>>>(lw, wf);
    k_xp<<<512, 256, 0, stream>>>(x, pw, pb, xpall);
    for (int d = 0; d <= 129; ++d){
      int lmin = (d > 127) ? (d - 127) : 0;
      int lmax = (d < 2) ? d : 2;
      int nst = lmax - lmin + 1;
      k_diag<<<64*nst, 128, 0, stream>>>(wf, lb, cbuf, hbuf, hrl, xpall, h2all, d, lmin);
    }
    k_out<<<256, 256, 0, stream>>>(h2all, ow, ob, dout);
  } else {
    // round-0 compact fallback
    size_t o2 = 0;
    auto carve2 = [&](size_t bytes){ char* p = ws + o2; o2 += (bytes + 255) & ~(size_t)255; return p; };
    unsigned short* wf0   = (unsigned short*)carve2(3ull*1024*2048*2);
    float*          cbuf0 = (float*)carve2(3ull*256*512*4);
    unsigned short* hbuf0 = (unsigned short*)carve2(2ull*3*256*512*2);
    hipMemsetAsync(cbuf0, 0, 3ull*256*512*4 + 2ull*3*256*512*2, stream);
    k_wconv0<<<3072, 256, 0, stream>>>(lw, wf0);
    k_iout<<<2048, 256, 0, stream>>>(dout, ob);
    for (int t = 0; t < T_; ++t)
      for (int l = 0; l < 3; ++l)
        k_stage0<<<512, 256, 0, stream>>>(x, pw, pb, wf0, lb, ow, dout,
                                          cbuf0, hbuf0, t, l);
  }
}